// Round 1
// 105.992 us; speedup vs baseline: 1.0002x; 1.0002x over previous
//
#include <hip/hip_runtime.h>
#include <math.h>

#define BB 4
#define NQ 512
#define NK 1024
#define DH 64
#define TQ 4                 // queries per block (was 8): grid 512 -> 2 blocks/CU
#define NWAVE 8
#define KPW (NK / NWAVE)     // 128 keys per wave

// ---------------- MLP: writes TRANSPOSED kT[b][d][j], qT[b][d][i] ----------------
// One 64-thread block per output row; lane = output dim e. relu on layer 1 only.
__global__ __launch_bounds__(64) void mlp_kernel(
    const float* __restrict__ x1, const float* __restrict__ x2,
    const float* __restrict__ Wk1, const float* __restrict__ bk1,
    const float* __restrict__ Wk2, const float* __restrict__ bk2,
    const float* __restrict__ Wq1, const float* __restrict__ bq1,
    const float* __restrict__ Wq2, const float* __restrict__ bq2,
    float* __restrict__ kT, float* __restrict__ qT)
{
    const int row  = blockIdx.x;
    const int lane = threadIdx.x;
    const float *x, *W1, *b1, *W2, *b2;
    float* out;   // transposed destination: out[lane * stride]
    if (row < BB * NK) {
        const int b = row / NK, j = row % NK;
        x = x1 + row * DH;
        W1 = Wk1; b1 = bk1; W2 = Wk2; b2 = bk2;
        out = kT + (size_t)b * DH * NK + j;           // + lane*NK below
    } else {
        const int rq = row - BB * NK;
        const int b = rq / NQ, i = rq % NQ;
        x = x2 + rq * DH;
        W1 = Wq1; b1 = bq1; W2 = Wq2; b2 = bq2;
        out = qT + (size_t)b * DH * NQ + i;           // + lane*NQ below
    }
    const int ostride = (row < BB * NK) ? NK : NQ;

    __shared__ float xs[DH];
    __shared__ float hs[DH];
    xs[lane] = x[lane];
    __syncthreads();
    float acc = b1[lane];
    #pragma unroll
    for (int d = 0; d < DH; ++d) acc = fmaf(xs[d], W1[d * DH + lane], acc);
    hs[lane] = fmaxf(acc, 0.0f);     // relu (not on last layer)
    __syncthreads();
    float acc2 = b2[lane];
    #pragma unroll
    for (int d = 0; d < DH; ++d) acc2 = fmaf(hs[d], W2[d * DH + lane], acc2);
    out[lane * ostride] = acc2;      // scattered dword store (transpose)
}

// ---------------- Laplace attention, two-pass softmax, LDS-minimal ----------------
// grid = B * (NQ/TQ) = 512 blocks, 512 threads = 8 waves -> 2 blocks/CU, 4 waves/SIMD.
// Score phase: wave w owns keys [w*128, w*128+128), lane holds keys j0=w*128+2*lane, j0+1.
//   kT[d][j] -> coalesced float2 VMEM; qT[d][i0..i0+3] -> wave-uniform (s_load_dwordx4).
// PV phase: lane = d, wave w owns same key range; p broadcast from LDS via b128;
//   r double-buffered in registers to hide L2 latency.
__global__ __launch_bounds__(512, 4) void attn_kernel(
    const float* __restrict__ kT, const float* __restrict__ qT,
    const float* __restrict__ rmat, float* __restrict__ outp)
{
    __shared__ float p_s[TQ * NK];          // 16 KB softmax weights; reused for partials
    __shared__ float wmin_s[NWAVE * TQ];
    __shared__ float wsum_s[NWAVE * TQ];

    const int t    = threadIdx.x;
    const int lane = t & 63;
    const int wav  = __builtin_amdgcn_readfirstlane(t >> 6);

    const int b  = blockIdx.x / (NQ / TQ);
    const int i0 = (blockIdx.x % (NQ / TQ)) * TQ;

    const float* kTb = kT + (size_t)b * DH * NK;
    const float* qTb = qT + (size_t)b * DH * NQ;

    const int j0 = wav * KPW + 2 * lane;    // this lane's two keys

    // ---- score phase: s[i] = sum_d |k[j] - q[i]| ----
    float s0[TQ], s1[TQ];
    #pragma unroll
    for (int i = 0; i < TQ; ++i) { s0[i] = 0.0f; s1[i] = 0.0f; }

    #pragma unroll 8
    for (int d = 0; d < DH; ++d) {
        const float2 kv = *(const float2*)&kTb[d * NK + j0];     // coalesced 512B, L2 hit
        const float* qrow = qTb + d * NQ + i0;                   // uniform -> s_load
        #pragma unroll
        for (int i = 0; i < TQ; ++i) {
            const float q = qrow[i];
            s0[i] += fabsf(kv.x - q);
            s1[i] += fabsf(kv.y - q);
        }
    }

    // ---- softmax pass 1: global min of s per query (max of -s) ----
    #pragma unroll
    for (int i = 0; i < TQ; ++i) {
        float m = fminf(s0[i], s1[i]);
        #pragma unroll
        for (int off = 32; off > 0; off >>= 1)
            m = fminf(m, __shfl_xor(m, off, 64));
        if (lane == 0) wmin_s[wav * TQ + i] = m;
    }
    __syncthreads();

    float M[TQ];
    #pragma unroll
    for (int i = 0; i < TQ; ++i) {
        float m = wmin_s[i];
        #pragma unroll
        for (int g = 1; g < NWAVE; ++g) m = fminf(m, wmin_s[g * TQ + i]);
        M[i] = m;
    }

    // ---- softmax pass 2: p = exp(M - s), per-query sums ----
    #pragma unroll
    for (int i = 0; i < TQ; ++i) {
        const float p0 = __expf(M[i] - s0[i]);
        const float p1 = __expf(M[i] - s1[i]);
        *(float2*)&p_s[i * NK + j0] = make_float2(p0, p1);       // contiguous b64 write
        float cs = p0 + p1;
        #pragma unroll
        for (int off = 32; off > 0; off >>= 1)
            cs += __shfl_xor(cs, off, 64);
        if (lane == 0) wsum_s[wav * TQ + i] = cs;
    }
    __syncthreads();

    // ---- PV: lane = d, wave w covers keys [w*128, w*128+128) ----
    float O[TQ];
    #pragma unroll
    for (int i = 0; i < TQ; ++i) O[i] = 0.0f;

    const float* rb = rmat + ((size_t)b * NK + wav * KPW) * DH + lane;
    // register double-buffer: prefetch next 4 r-values while FMA-ing current 4
    float rn0 = rb[0 * DH], rn1 = rb[1 * DH], rn2 = rb[2 * DH], rn3 = rb[3 * DH];
    #pragma unroll 2
    for (int jj = 0; jj < KPW; jj += 4) {
        const float rv0 = rn0, rv1 = rn1, rv2 = rn2, rv3 = rn3;
        const int jn = (jj + 4 < KPW) ? (jj + 4) : 0;            // branchless clamp
        rn0 = rb[(jn + 0) * DH];
        rn1 = rb[(jn + 1) * DH];
        rn2 = rb[(jn + 2) * DH];
        rn3 = rb[(jn + 3) * DH];
        #pragma unroll
        for (int i = 0; i < TQ; ++i) {
            const float4 p4 = *(const float4*)&p_s[i * NK + wav * KPW + jj]; // broadcast b128
            O[i] = fmaf(p4.x, rv0, O[i]);
            O[i] = fmaf(p4.y, rv1, O[i]);
            O[i] = fmaf(p4.z, rv2, O[i]);
            O[i] = fmaf(p4.w, rv3, O[i]);
        }
    }
    __syncthreads();    // all waves done reading p_s

    // ---- cross-wave combine (reuse p_s region): 8 waves x 4 queries x 64 dims ----
    float* part = p_s;  // needs 8*4*64 = 2048 floats <= 4096
    #pragma unroll
    for (int i = 0; i < TQ; ++i)
        part[(wav * TQ + i) * 64 + lane] = O[i];
    __syncthreads();

    if (wav < TQ) {     // waves 0..3 each own one query
        float myl = 0.0f;
        #pragma unroll
        for (int g = 0; g < NWAVE; ++g) myl += wsum_s[g * TQ + wav];
        float sum = 0.0f;
        #pragma unroll
        for (int g = 0; g < NWAVE; ++g) sum += part[(g * TQ + wav) * 64 + lane];
        outp[((size_t)b * NQ + i0 + wav) * DH + lane] = sum / myl;
    }
}

extern "C" void kernel_launch(void* const* d_in, const int* in_sizes, int n_in,
                              void* d_out, int out_size, void* d_ws, size_t ws_size,
                              hipStream_t stream) {
    const float* x1  = (const float*)d_in[0];
    const float* x2  = (const float*)d_in[1];
    const float* r   = (const float*)d_in[2];
    const float* Wk1 = (const float*)d_in[3];
    const float* bk1 = (const float*)d_in[4];
    const float* Wk2 = (const float*)d_in[5];
    const float* bk2 = (const float*)d_in[6];
    const float* Wq1 = (const float*)d_in[7];
    const float* bq1 = (const float*)d_in[8];
    const float* Wq2 = (const float*)d_in[9];
    const float* bq2 = (const float*)d_in[10];
    float* out  = (float*)d_out;

    float* kT = (float*)d_ws;                     // B*DH*NK floats (transposed keys)
    float* qT = kT + (size_t)BB * DH * NK;        // B*DH*NQ floats (transposed queries)

    mlp_kernel<<<BB * (NK + NQ), 64, 0, stream>>>(
        x1, x2, Wk1, bk1, Wk2, bk2, Wq1, bq1, Wq2, bq2, kT, qT);

    attn_kernel<<<BB * (NQ / TQ), 512, 0, stream>>>(kT, qT, r, out);
}